// Round 21
// baseline (340.546 us; speedup 1.0000x reference)
//
#include <hip/hip_runtime.h>

constexpr int Cc = 512;
constexpr int Nn = 4096;   // 64*64
constexpr int Bb = 4;
#define EPS 1e-5f

using f16x8 = __attribute__((ext_vector_type(8))) _Float16;
using f32x4 = __attribute__((ext_vector_type(4))) float;
typedef unsigned short us;
typedef unsigned long long ull;

__device__ __forceinline__ us f2h(float f) {
    union { _Float16 h; us u; } v; v.h = (_Float16)f;
    return v.u;
}
__device__ __forceinline__ void gload_lds16(const void* g, void* l) {
    __builtin_amdgcn_global_load_lds(
        (const __attribute__((address_space(1))) void*)g,
        (__attribute__((address_space(3))) void*)l, 16, 0, 0);
}
template <int N> __device__ __forceinline__ void wait_vmcnt() {
    if constexpr (N == 0)      asm volatile("s_waitcnt vmcnt(0)" ::: "memory");
    else if constexpr (N == 2) asm volatile("s_waitcnt vmcnt(2)" ::: "memory");
    else if constexpr (N == 4) asm volatile("s_waitcnt vmcnt(4)" ::: "memory");
    else if constexpr (N == 8) asm volatile("s_waitcnt vmcnt(8)" ::: "memory");
    else                       asm volatile("s_waitcnt vmcnt(16)" ::: "memory");
}
__device__ __forceinline__ void cfence() { asm volatile("" ::: "memory"); }

// ---- stats for BOTH tensors in one launch: per (b,c) mean & rstd (ddof=1) ----
__global__ __launch_bounds__(256) void stats2_kernel(const float* __restrict__ x0,
                                                     const float* __restrict__ x1,
                                                     float* __restrict__ mean0,
                                                     float* __restrict__ rstd0,
                                                     float* __restrict__ mean1,
                                                     float* __restrict__ rstd1) {
    int bc = blockIdx.x;
    const float* row;
    float *mean, *rstd;
    int idx;
    if (bc < Bb * Cc) { idx = bc; row = x0 + (size_t)idx * Nn; mean = mean0; rstd = rstd0; }
    else              { idx = bc - Bb * Cc; row = x1 + (size_t)idx * Nn; mean = mean1; rstd = rstd1; }
    float s = 0.f, sq = 0.f;
    for (int i = threadIdx.x * 4; i < Nn; i += 256 * 4) {
        float4 v = *reinterpret_cast<const float4*>(row + i);
        s  += v.x + v.y + v.z + v.w;
        sq += v.x*v.x + v.y*v.y + v.z*v.z + v.w*v.w;
    }
    for (int off = 32; off; off >>= 1) {
        s  += __shfl_down(s, off);
        sq += __shfl_down(sq, off);
    }
    __shared__ float ls[4], lsq[4];
    int wid = threadIdx.x >> 6;
    if ((threadIdx.x & 63) == 0) { ls[wid] = s; lsq[wid] = sq; }
    __syncthreads();
    if (threadIdx.x == 0) {
        float S  = ls[0] + ls[1] + ls[2] + ls[3];
        float SQ = lsq[0] + lsq[1] + lsq[2] + lsq[3];
        float m  = S / (float)Nn;
        float var = (SQ - S * m) / (float)(Nn - 1);
        mean[idx] = m;
        rstd[idx] = rsqrtf(var + EPS);
    }
}

// ------ pack fp32 [b][c][n] -> fp16 transposed [b][n][c], inst-norm ------
__global__ __launch_bounds__(256) void pack_T(const float* __restrict__ X,
                                              const float* __restrict__ mean,
                                              const float* __restrict__ rstd,
                                              us* __restrict__ T0) {
    int b = blockIdx.z;
    int n0 = blockIdx.x * 64, c0 = blockIdx.y * 64;
    __shared__ float tile[64][65];
    const float* Xb = X + (size_t)b * Cc * Nn;
    for (int i = threadIdx.x; i < 64 * 64; i += 256) {
        int c = i >> 6, n = i & 63;
        float v = Xb[(size_t)(c0 + c) * Nn + n0 + n];
        int cg = b * Cc + c0 + c;
        tile[c][n] = (v - mean[cg]) * rstd[cg];
    }
    __syncthreads();
    us* Pb = T0 + (size_t)b * Nn * Cc;
    for (int i = threadIdx.x; i < 64 * 64; i += 256) {
        int n = i >> 6, c = i & 63;
        Pb[(size_t)(n0 + n) * Cc + c0 + c] = f2h(tile[c][n]);
    }
}

// ------ style: ONE read -> normed SN and raw SR, both fp16 [b][n][c] ------
__global__ __launch_bounds__(256) void pack_style(const float* __restrict__ X,
                                                  const float* __restrict__ mean,
                                                  const float* __restrict__ rstd,
                                                  us* __restrict__ SNo,
                                                  us* __restrict__ SRo) {
    int b = blockIdx.z;
    int n0 = blockIdx.x * 64, c0 = blockIdx.y * 64;
    __shared__ float tile[64][65];
    const float* Xb = X + (size_t)b * Cc * Nn;
    for (int i = threadIdx.x; i < 64 * 64; i += 256) {
        int c = i >> 6, n = i & 63;
        tile[c][n] = Xb[(size_t)(c0 + c) * Nn + n0 + n];   // raw
    }
    __syncthreads();
    us* Nb = SNo + (size_t)b * Nn * Cc;
    us* Rb = SRo + (size_t)b * Nn * Cc;
    for (int i = threadIdx.x; i < 64 * 64; i += 256) {
        int n = i >> 6, c = i & 63;
        float raw = tile[c][n];
        int cg = b * Cc + c0 + c;
        size_t off = (size_t)(n0 + n) * Cc + c0 + c;
        Rb[off] = f2h(raw);
        Nb[off] = f2h((raw - mean[cg]) * rstd[cg]);
    }
}

// ------ pack the four 512x512 weights to fp16 ------
__global__ __launch_bounds__(256) void pack_w(const float* __restrict__ fw, const float* __restrict__ gw,
                                              const float* __restrict__ hw, const float* __restrict__ ow,
                                              us* __restrict__ fo, us* __restrict__ go,
                                              us* __restrict__ ho, us* __restrict__ oo) {
    int i = blockIdx.x * 256 + threadIdx.x;
    if (i >= Cc * Cc) return;
    fo[i] = f2h(fw[i]);
    go[i] = f2h(gw[i]);
    ho[i] = f2h(hw[i]);
    oo[i] = f2h(ow[i]);
}

// ------------- fp16 MFMA GEMM (4-wave): C[m][n'] = sum_k A[m][k]*B[n'][k] ------
// 3-BUFFER pipeline with COUNTED vmcnt (T4): tiles t+1,t+2 stay in flight
// across raw s_barriers; never drain to 0 in the main loop. Buffer t is
// overwritten only at iter t+1, after the post-compute barrier.
// XOR swizzle on staged tiles; LDS-staged vectorized epilogue.
template <int EPI, int BIAS, bool RESID, int BM, int BN, int BK, int SWZ>
__global__ __launch_bounds__(256) void mfma_gemm(
    const us* __restrict__ A, int lda, long long strideA,
    const us* __restrict__ B, int ldb, long long strideB,
    void* __restrict__ out0, int ldc, long long strideC,
    const float* __restrict__ bias, const float* __restrict__ resid, long long strideR,
    int K) {
    constexpr int WM = BM / 2, WN = BN / 2;
    constexpr int MI = WM / 16, NI = WN / 16;
    constexpr int AE = BM * BK, BE = BN * BK;
    constexpr int BUFSZ = AE + BE;
    constexpr int ACH = AE / 512, BCH = BE / 512;
    constexpr int LPT = (ACH + BCH) / 4;       // loads per thread per stage
    __shared__ __attribute__((aligned(16))) us smem[3 * BUFSZ];

    int bz = blockIdx.z;
    const us* Ab = A + (size_t)bz * strideA;
    const us* Bbp = B + (size_t)bz * strideB;

    int bx = blockIdx.x, by = blockIdx.y;
    if constexpr (SWZ == 1) {
        int nwg = gridDim.x * gridDim.y;
        int bid = blockIdx.x + gridDim.x * blockIdx.y;
        int cpx = nwg >> 3;
        int swz = (bid & 7) * cpx + (bid >> 3);
        bx = swz % gridDim.x;
        by = swz / gridDim.x;
    } else if constexpr (SWZ == 2) {
        int bid = blockIdx.x + gridDim.x * blockIdx.y;
        int xcd = bid & 7;
        int idx = bid >> 3;
        int rpr = gridDim.y >> 2;
        int cpr = gridDim.x >> 1;
        int row0 = (xcd >> 1) * rpr;
        int col0 = (xcd & 1) * cpr;
        by = row0 + idx / cpr;
        bx = col0 + idx % cpr;
    }
    int m0 = by * BM, n0 = bx * BN;
    int tid = threadIdx.x, wave = tid >> 6, lane = tid & 63;
    int wr = wave >> 1, wc = wave & 1;
    int lr = lane & 15, lg = lane >> 4;

    auto stage = [&](int buf, int k0) {
        us* Asb = smem + buf * BUFSZ;
        us* Bsb = Asb + AE;
#pragma unroll
        for (int ch = wave; ch < ACH; ch += 4) {
            int e0 = ch * 512 + lane * 8;
            int kb = e0 / (BM * 32);
            int rem = e0 - kb * (BM * 32);
            int rr = rem >> 5;
            int gslot = ((rem & 31) >> 3) ^ ((rr >> 1) & 3);
            gload_lds16(Ab + (size_t)(m0 + rr) * lda + k0 + kb * 32 + gslot * 8,
                        Asb + ch * 512);
        }
#pragma unroll
        for (int ch = wave; ch < BCH; ch += 4) {
            int e0 = ch * 512 + lane * 8;
            int kb = e0 / (BN * 32);
            int rem = e0 - kb * (BN * 32);
            int rr = rem >> 5;
            int gslot = ((rem & 31) >> 3) ^ ((rr >> 1) & 3);
            gload_lds16(Bbp + (size_t)(n0 + rr) * ldb + k0 + kb * 32 + gslot * 8,
                        Bsb + ch * 512);
        }
    };

    f32x4 acc[MI][NI];
#pragma unroll
    for (int i = 0; i < MI; ++i)
#pragma unroll
        for (int j = 0; j < NI; ++j) acc[i][j] = (f32x4){0.f, 0.f, 0.f, 0.f};

    int nsteps = K / BK;
    stage(0, 0);
    if (nsteps > 1) stage(1, BK);

    for (int t = 0; t < nsteps; ++t) {
        if (t + 2 < nsteps) {
            stage((t + 2) % 3, (t + 2) * BK);
            wait_vmcnt<2 * LPT>();             // tile t landed; t+1,t+2 in flight
        } else if (t + 1 < nsteps) {
            wait_vmcnt<LPT>();
        } else {
            wait_vmcnt<0>();
        }
        __builtin_amdgcn_s_barrier();          // all waves see tile t
        cfence();
        const us* As = smem + (t % 3) * BUFSZ;
        const us* Bs = As + AE;
#pragma unroll
        for (int kb = 0; kb < BK / 32; ++kb) {
            const us* Abase = As + kb * BM * 32;
            const us* Bbase = Bs + kb * BN * 32;
            f16x8 a[MI], b[NI];
#pragma unroll
            for (int x = 0; x < MI; ++x) {
                int row = wr * WM + x * 16 + lr;
                a[x] = *reinterpret_cast<const f16x8*>(
                    &Abase[row * 32 + ((lg ^ ((row >> 1) & 3)) << 3)]);
            }
#pragma unroll
            for (int x = 0; x < NI; ++x) {
                int row = wc * WN + x * 16 + lr;
                b[x] = *reinterpret_cast<const f16x8*>(
                    &Bbase[row * 32 + ((lg ^ ((row >> 1) & 3)) << 3)]);
            }
#pragma unroll
            for (int mi = 0; mi < MI; ++mi)
#pragma unroll
                for (int ni = 0; ni < NI; ++ni)
                    acc[mi][ni] = __builtin_amdgcn_mfma_f32_16x16x32_f16(a[mi], b[ni], acc[mi][ni], 0, 0, 0);
        }
        __builtin_amdgcn_s_barrier();          // buf t free for overwrite
        cfence();
    }

    constexpr int SP = BN + 4;
    float* sst = reinterpret_cast<float*>(smem);
    constexpr int CSEG = BN / 8;
    int rl = tid >> 3;
    int cb = (tid & 7) * CSEG;
#pragma unroll
    for (int mi = 0; mi < MI; ++mi) {
        __syncthreads();
#pragma unroll
        for (int ni = 0; ni < NI; ++ni) {
#pragma unroll
            for (int r = 0; r < 4; ++r)
                sst[(wr * 16 + lg * 4 + r) * SP + wc * WN + ni * 16 + lr] = acc[mi][ni][r];
        }
        __syncthreads();
        int grow = m0 + (rl >> 4) * WM + mi * 16 + (rl & 15);
        float bs = 0.f;
        if constexpr (BIAS == 1) bs = bias[grow];
#pragma unroll
        for (int j = 0; j < CSEG / 4; ++j) {
            int col = n0 + cb + j * 4;
            float4 v = *reinterpret_cast<const float4*>(&sst[rl * SP + cb + j * 4]);
            if constexpr (BIAS == 1) { v.x += bs; v.y += bs; v.z += bs; v.w += bs; }
            if constexpr (BIAS == 2) {
                const float4 bv = *reinterpret_cast<const float4*>(&bias[col]);
                v.x += bv.x; v.y += bv.y; v.z += bv.z; v.w += bv.w;
            }
            size_t off = (size_t)bz * strideC + (size_t)grow * ldc + col;
            if constexpr (RESID) {
                const float4 rr4 = *reinterpret_cast<const float4*>(
                    &resid[(size_t)bz * strideR + (size_t)grow * ldc + col]);
                v.x += rr4.x; v.y += rr4.y; v.z += rr4.z; v.w += rr4.w;
            }
            if constexpr (EPI == 0) {
                *reinterpret_cast<float4*>(&((float*)out0)[off]) = v;
            } else {
                ull pk = (ull)f2h(v.x) | ((ull)f2h(v.y) << 16)
                       | ((ull)f2h(v.z) << 32) | ((ull)f2h(v.w) << 48);
                *reinterpret_cast<ull*>(&((us*)out0)[off]) = pk;
            }
        }
    }
}

// ------- fp16 MFMA GEMM (8-wave, 256x256, wave tile 128x64), 3-buffer counted ----
template <int SWZ>
__global__ __launch_bounds__(512) void mfma_gemm8w(
    const us* __restrict__ A, int lda, long long strideA,
    const us* __restrict__ B, int ldb, long long strideB,
    us* __restrict__ out0, int ldc, long long strideC,
    int K) {
    constexpr int BM = 256, BN = 256, BK = 32;
    constexpr int WM = 128, WN = 64;
    constexpr int MI = WM / 16, NI = WN / 16;  // 8, 4
    constexpr int AE = BM * BK, BE = BN * BK;
    constexpr int BUFSZ = AE + BE;             // 16384 elems = 32KB
    constexpr int ACH = AE / 512, BCH = BE / 512;   // 16, 16
    constexpr int LPT = (ACH + BCH) / 8;       // 4 loads/thread/stage
    __shared__ __attribute__((aligned(16))) us smem[3 * BUFSZ];   // 96KB

    int bz = blockIdx.z;
    const us* Ab = A + (size_t)bz * strideA;
    const us* Bbp = B + (size_t)bz * strideB;

    int bx = blockIdx.x, by = blockIdx.y;
    if constexpr (SWZ == 2) {
        int bid = blockIdx.x + gridDim.x * blockIdx.y;
        int xcd = bid & 7;
        int idx = bid >> 3;
        int rpr = gridDim.y >> 2;
        int cpr = gridDim.x >> 1;
        int row0 = (xcd >> 1) * rpr;
        int col0 = (xcd & 1) * cpr;
        by = row0 + idx / cpr;
        bx = col0 + idx % cpr;
    }
    int m0 = by * BM, n0 = bx * BN;
    int tid = threadIdx.x, wave = tid >> 6, lane = tid & 63;
    int wr = wave >> 2, wc = wave & 3;
    int lr = lane & 15, lg = lane >> 4;

    auto stage = [&](int buf, int k0) {
        us* Asb = smem + buf * BUFSZ;
        us* Bsb = Asb + AE;
#pragma unroll
        for (int ch = wave; ch < ACH; ch += 8) {
            int e0 = ch * 512 + lane * 8;
            int rr = e0 >> 5;
            int gslot = ((e0 & 31) >> 3) ^ ((rr >> 1) & 3);
            gload_lds16(Ab + (size_t)(m0 + rr) * lda + k0 + gslot * 8,
                        Asb + ch * 512);
        }
#pragma unroll
        for (int ch = wave; ch < BCH; ch += 8) {
            int e0 = ch * 512 + lane * 8;
            int rr = e0 >> 5;
            int gslot = ((e0 & 31) >> 3) ^ ((rr >> 1) & 3);
            gload_lds16(Bbp + (size_t)(n0 + rr) * ldb + k0 + gslot * 8,
                        Bsb + ch * 512);
        }
    };

    f32x4 acc[MI][NI];
#pragma unroll
    for (int i = 0; i < MI; ++i)
#pragma unroll
        for (int j = 0; j < NI; ++j) acc[i][j] = (f32x4){0.f, 0.f, 0.f, 0.f};

    int nsteps = K / BK;
    stage(0, 0);
    if (nsteps > 1) stage(1, BK);

    for (int t = 0; t < nsteps; ++t) {
        if (t + 2 < nsteps) {
            stage((t + 2) % 3, (t + 2) * BK);
            wait_vmcnt<2 * LPT>();
        } else if (t + 1 < nsteps) {
            wait_vmcnt<LPT>();
        } else {
            wait_vmcnt<0>();
        }
        __builtin_amdgcn_s_barrier();
        cfence();
        const us* As = smem + (t % 3) * BUFSZ;
        const us* Bs = As + AE;
        f16x8 a[MI], b[NI];
#pragma unroll
        for (int x = 0; x < MI; ++x) {
            int row = wr * WM + x * 16 + lr;
            a[x] = *reinterpret_cast<const f16x8*>(
                &As[row * 32 + ((lg ^ ((row >> 1) & 3)) << 3)]);
        }
#pragma unroll
        for (int x = 0; x < NI; ++x) {
            int row = wc * WN + x * 16 + lr;
            b[x] = *reinterpret_cast<const f16x8*>(
                &Bs[row * 32 + ((lg ^ ((row >> 1) & 3)) << 3)]);
        }
#pragma unroll
        for (int mi = 0; mi < MI; ++mi)
#pragma unroll
            for (int ni = 0; ni < NI; ++ni)
                acc[mi][ni] = __builtin_amdgcn_mfma_f32_16x16x32_f16(a[mi], b[ni], acc[mi][ni], 0, 0, 0);
        __builtin_amdgcn_s_barrier();
        cfence();
    }

#pragma unroll
    for (int mi = 0; mi < MI; ++mi) {
        int row = m0 + wr * WM + mi * 16 + lg * 4;
#pragma unroll
        for (int ni = 0; ni < NI; ++ni) {
            int col = n0 + wc * WN + ni * 16 + lr;
#pragma unroll
            for (int r = 0; r < 4; ++r) {
                size_t off = (size_t)bz * strideC + (size_t)(row + r) * ldc + col;
                out0[off] = f2h(acc[mi][ni][r]);
            }
        }
    }
}

// ------- row softmax fp16 IN-PLACE (S row -> normalized P row) -------
__global__ __launch_bounds__(256) void softmax_kernel(us* __restrict__ S) {
    us* rowp = S + (size_t)blockIdx.y * ((size_t)Nn * Nn) + (size_t)blockIdx.x * Nn;
    f16x8* r8 = reinterpret_cast<f16x8*>(rowp);
    int t = threadIdx.x;
    float f[16];
    float mx = -1e30f;
#pragma unroll
    for (int j = 0; j < 2; ++j) {
        f16x8 v = r8[t + 256 * j];
#pragma unroll
        for (int e = 0; e < 8; ++e) {
            f[j * 8 + e] = (float)v[e];
            mx = fmaxf(mx, f[j * 8 + e]);
        }
    }
    for (int off = 32; off; off >>= 1) mx = fmaxf(mx, __shfl_down(mx, off));
    __shared__ float redm[4], reds[4];
    int wid = t >> 6;
    if ((t & 63) == 0) redm[wid] = mx;
    __syncthreads();
    mx = fmaxf(fmaxf(redm[0], redm[1]), fmaxf(redm[2], redm[3]));
    float s = 0.f;
#pragma unroll
    for (int j = 0; j < 16; ++j) {
        f[j] = __expf(f[j] - mx);
        s += f[j];
    }
    for (int off = 32; off; off >>= 1) s += __shfl_down(s, off);
    if ((t & 63) == 0) reds[wid] = s;
    __syncthreads();
    s = reds[0] + reds[1] + reds[2] + reds[3];
    float inv = 1.f / s;
#pragma unroll
    for (int j = 0; j < 2; ++j) {
        f16x8 o;
#pragma unroll
        for (int e = 0; e < 8; ++e) o[e] = (_Float16)(f[j * 8 + e] * inv);
        r8[t + 256 * j] = o;
    }
}

extern "C" void kernel_launch(void* const* d_in, const int* in_sizes, int n_in,
                              void* d_out, int out_size, void* d_ws, size_t ws_size,
                              hipStream_t stream) {
    const float* content = (const float*)d_in[0];
    const float* style   = (const float*)d_in[1];
    const float* f_w = (const float*)d_in[2];
    const float* f_b = (const float*)d_in[3];
    const float* g_w = (const float*)d_in[4];
    const float* g_b = (const float*)d_in[5];
    const float* h_w = (const float*)d_in[6];
    const float* h_b = (const float*)d_in[7];
    const float* o_w = (const float*)d_in[8];
    const float* o_b = (const float*)d_in[9];
    float* out = (float*)d_out;
    char* ws = (char*)d_ws;

    const size_t PB   = (size_t)Cc * Nn;
    const size_t TEN  = PB * Bb;
    const size_t SMAT = (size_t)Nn * Nn;

    us* FT  = (us*)ws;
    us* GT  = FT + TEN;
    us* Hbf = GT + TEN;
    us* OT  = Hbf + TEN;
    us* fwh = OT + TEN;
    us* gwh = fwh + Cc * Cc;
    us* hwb = gwh + Cc * Cc;
    us* owb = hwb + Cc * Cc;
    float* meanC = (float*)(owb + Cc * Cc);
    float* rstdC = meanC + Bb * Cc;
    float* meanS = rstdC + Bb * Cc;
    float* rstdS = meanS + Bb * Cc;
    us* CN = (us*)(rstdS + Bb * Cc);
    us* SN = CN + TEN;
    us* SR = SN + TEN;
    us* S4 = CN;   // overlays dead CN/SN/SR after convs

    stats2_kernel<<<2 * Bb * Cc, 256, 0, stream>>>(content, style,
                                                   meanC, rstdC, meanS, rstdS);

    dim3 pgrid(Nn / 64, Cc / 64, Bb);
    pack_T<<<pgrid, 256, 0, stream>>>(content, meanC, rstdC, CN);
    pack_style<<<pgrid, 256, 0, stream>>>(style, meanS, rstdS, SN, SR);
    pack_w<<<(Cc * Cc + 255) / 256, 256, 0, stream>>>(f_w, g_w, h_w, o_w,
                                                      fwh, gwh, hwb, owb);

    // F^T[q][c'] = sum_c CN[q][c] f_w[c'][c] + f_b[c']
    mfma_gemm<1, 2, false, 64, 64, 32, 1><<<dim3(Cc / 64, Nn / 64, Bb), 256, 0, stream>>>(
        CN, Cc, (long long)PB, fwh, Cc, 0,
        FT, Cc, (long long)PB, f_b, nullptr, 0, Cc);
    // G^T likewise
    mfma_gemm<1, 2, false, 64, 64, 32, 1><<<dim3(Cc / 64, Nn / 64, Bb), 256, 0, stream>>>(
        SN, Cc, (long long)PB, gwh, Cc, 0,
        GT, Cc, (long long)PB, g_b, nullptr, 0, Cc);
    // H[c'][s]
    mfma_gemm<1, 1, false, 64, 64, 32, 1><<<dim3(Nn / 64, Cc / 64, Bb), 256, 0, stream>>>(
        hwb, Cc, 0, SR, Cc, (long long)PB,
        Hbf, Nn, (long long)PB, h_b, nullptr, 0, Cc);

    // S[q][s] = F^T . G^T  (M=N=4096,K=512): 8-wave 256x256, 3-buffer counted
    mfma_gemm8w<2><<<dim3(Nn / 256, Nn / 256, Bb), 512, 0, stream>>>(
        FT, Cc, (long long)PB, GT, Cc, (long long)PB,
        S4, Nn, (long long)SMAT, Cc);
    softmax_kernel<<<dim3(Nn, Bb), 256, 0, stream>>>(S4);
    // O^T[q][c'] = P . H  (M=4096,N=512,K=4096): 128x128, BK=32, 3 blocks/CU
    mfma_gemm<1, 0, false, 128, 128, 32, 2><<<dim3(Cc / 128, Nn / 128, Bb), 256, 0, stream>>>(
        S4, Nn, (long long)SMAT, Hbf, Nn, (long long)PB,
        OT, Cc, (long long)PB, nullptr, nullptr, 0, Nn);

    // out = o_w . O^T + o_b + content
    mfma_gemm<0, 1, true, 64, 64, 32, 1><<<dim3(Nn / 64, Cc / 64, Bb), 256, 0, stream>>>(
        owb, Cc, 0, OT, Cc, (long long)PB,
        out, Nn, (long long)PB, o_b, content, (long long)PB, Cc);
}

// Round 22
// 327.911 us; speedup vs baseline: 1.0385x; 1.0385x over previous
//
#include <hip/hip_runtime.h>

constexpr int Cc = 512;
constexpr int Nn = 4096;   // 64*64
constexpr int Bb = 4;
#define EPS 1e-5f

using f16x8 = __attribute__((ext_vector_type(8))) _Float16;
using f32x4 = __attribute__((ext_vector_type(4))) float;
typedef unsigned short us;
typedef unsigned long long ull;

__device__ __forceinline__ us f2h(float f) {
    union { _Float16 h; us u; } v; v.h = (_Float16)f;
    return v.u;
}
__device__ __forceinline__ void gload_lds16(const void* g, void* l) {
    __builtin_amdgcn_global_load_lds(
        (const __attribute__((address_space(1))) void*)g,
        (__attribute__((address_space(3))) void*)l, 16, 0, 0);
}

// ---- stats for BOTH tensors in one launch: per (b,c) mean & rstd (ddof=1) ----
__global__ __launch_bounds__(256) void stats2_kernel(const float* __restrict__ x0,
                                                     const float* __restrict__ x1,
                                                     float* __restrict__ mean0,
                                                     float* __restrict__ rstd0,
                                                     float* __restrict__ mean1,
                                                     float* __restrict__ rstd1) {
    int bc = blockIdx.x;
    const float* row;
    float *mean, *rstd;
    int idx;
    if (bc < Bb * Cc) { idx = bc; row = x0 + (size_t)idx * Nn; mean = mean0; rstd = rstd0; }
    else              { idx = bc - Bb * Cc; row = x1 + (size_t)idx * Nn; mean = mean1; rstd = rstd1; }
    float s = 0.f, sq = 0.f;
    for (int i = threadIdx.x * 4; i < Nn; i += 256 * 4) {
        float4 v = *reinterpret_cast<const float4*>(row + i);
        s  += v.x + v.y + v.z + v.w;
        sq += v.x*v.x + v.y*v.y + v.z*v.z + v.w*v.w;
    }
    for (int off = 32; off; off >>= 1) {
        s  += __shfl_down(s, off);
        sq += __shfl_down(sq, off);
    }
    __shared__ float ls[4], lsq[4];
    int wid = threadIdx.x >> 6;
    if ((threadIdx.x & 63) == 0) { ls[wid] = s; lsq[wid] = sq; }
    __syncthreads();
    if (threadIdx.x == 0) {
        float S  = ls[0] + ls[1] + ls[2] + ls[3];
        float SQ = lsq[0] + lsq[1] + lsq[2] + lsq[3];
        float m  = S / (float)Nn;
        float var = (SQ - S * m) / (float)(Nn - 1);
        mean[idx] = m;
        rstd[idx] = rsqrtf(var + EPS);
    }
}

// ------ pack fp32 [b][c][n] -> fp16 transposed [b][n][c], inst-norm ------
__global__ __launch_bounds__(256) void pack_T(const float* __restrict__ X,
                                              const float* __restrict__ mean,
                                              const float* __restrict__ rstd,
                                              us* __restrict__ T0) {
    int b = blockIdx.z;
    int n0 = blockIdx.x * 64, c0 = blockIdx.y * 64;
    __shared__ float tile[64][65];
    const float* Xb = X + (size_t)b * Cc * Nn;
    for (int i = threadIdx.x; i < 64 * 64; i += 256) {
        int c = i >> 6, n = i & 63;
        float v = Xb[(size_t)(c0 + c) * Nn + n0 + n];
        int cg = b * Cc + c0 + c;
        tile[c][n] = (v - mean[cg]) * rstd[cg];
    }
    __syncthreads();
    us* Pb = T0 + (size_t)b * Nn * Cc;
    for (int i = threadIdx.x; i < 64 * 64; i += 256) {
        int n = i >> 6, c = i & 63;
        Pb[(size_t)(n0 + n) * Cc + c0 + c] = f2h(tile[c][n]);
    }
}

// ------ style: ONE read -> normed SN and raw SR, both fp16 [b][n][c] ------
__global__ __launch_bounds__(256) void pack_style(const float* __restrict__ X,
                                                  const float* __restrict__ mean,
                                                  const float* __restrict__ rstd,
                                                  us* __restrict__ SNo,
                                                  us* __restrict__ SRo) {
    int b = blockIdx.z;
    int n0 = blockIdx.x * 64, c0 = blockIdx.y * 64;
    __shared__ float tile[64][65];
    const float* Xb = X + (size_t)b * Cc * Nn;
    for (int i = threadIdx.x; i < 64 * 64; i += 256) {
        int c = i >> 6, n = i & 63;
        tile[c][n] = Xb[(size_t)(c0 + c) * Nn + n0 + n];   // raw
    }
    __syncthreads();
    us* Nb = SNo + (size_t)b * Nn * Cc;
    us* Rb = SRo + (size_t)b * Nn * Cc;
    for (int i = threadIdx.x; i < 64 * 64; i += 256) {
        int n = i >> 6, c = i & 63;
        float raw = tile[c][n];
        int cg = b * Cc + c0 + c;
        size_t off = (size_t)(n0 + n) * Cc + c0 + c;
        Rb[off] = f2h(raw);
        Nb[off] = f2h((raw - mean[cg]) * rstd[cg]);
    }
}

// ------ pack the four 512x512 weights to fp16 ------
__global__ __launch_bounds__(256) void pack_w(const float* __restrict__ fw, const float* __restrict__ gw,
                                              const float* __restrict__ hw, const float* __restrict__ ow,
                                              us* __restrict__ fo, us* __restrict__ go,
                                              us* __restrict__ ho, us* __restrict__ oo) {
    int i = blockIdx.x * 256 + threadIdx.x;
    if (i >= Cc * Cc) return;
    fo[i] = f2h(fw[i]);
    go[i] = f2h(gw[i]);
    ho[i] = f2h(hw[i]);
    oo[i] = f2h(ow[i]);
}

// ------------- fp16 MFMA GEMM (4-wave): C[m][n'] = sum_k A[m][k]*B[n'][k] ------
// Double-buffered LDS, XOR swizzle, LDS-staged epilogue (r17/r20 structure).
template <int EPI, int BIAS, bool RESID, int BM, int BN, int BK, int SWZ>
__global__ __launch_bounds__(256) void mfma_gemm(
    const us* __restrict__ A, int lda, long long strideA,
    const us* __restrict__ B, int ldb, long long strideB,
    void* __restrict__ out0, int ldc, long long strideC,
    const float* __restrict__ bias, const float* __restrict__ resid, long long strideR,
    int K) {
    constexpr int WM = BM / 2, WN = BN / 2;
    constexpr int MI = WM / 16, NI = WN / 16;
    constexpr int AE = BM * BK, BE = BN * BK;
    constexpr int BUFSZ = AE + BE;
    constexpr int ACH = AE / 512, BCH = BE / 512;
    __shared__ __attribute__((aligned(16))) us smem[2 * BUFSZ];

    int bz = blockIdx.z;
    const us* Ab = A + (size_t)bz * strideA;
    const us* Bbp = B + (size_t)bz * strideB;

    int bx = blockIdx.x, by = blockIdx.y;
    if constexpr (SWZ == 1) {
        int nwg = gridDim.x * gridDim.y;
        int bid = blockIdx.x + gridDim.x * blockIdx.y;
        int cpx = nwg >> 3;
        int swz = (bid & 7) * cpx + (bid >> 3);
        bx = swz % gridDim.x;
        by = swz / gridDim.x;
    } else if constexpr (SWZ == 2) {
        int bid = blockIdx.x + gridDim.x * blockIdx.y;
        int xcd = bid & 7;
        int idx = bid >> 3;
        int rpr = gridDim.y >> 2;
        int cpr = gridDim.x >> 1;
        int row0 = (xcd >> 1) * rpr;
        int col0 = (xcd & 1) * cpr;
        by = row0 + idx / cpr;
        bx = col0 + idx % cpr;
    }
    int m0 = by * BM, n0 = bx * BN;
    int tid = threadIdx.x, wave = tid >> 6, lane = tid & 63;
    int wr = wave >> 1, wc = wave & 1;
    int lr = lane & 15, lg = lane >> 4;

    auto stage = [&](int buf, int k0) {
        us* Asb = smem + buf * BUFSZ;
        us* Bsb = Asb + AE;
#pragma unroll
        for (int ch = wave; ch < ACH; ch += 4) {
            int e0 = ch * 512 + lane * 8;
            int kb = e0 / (BM * 32);
            int rem = e0 - kb * (BM * 32);
            int rr = rem >> 5;
            int gslot = ((rem & 31) >> 3) ^ ((rr >> 1) & 3);
            gload_lds16(Ab + (size_t)(m0 + rr) * lda + k0 + kb * 32 + gslot * 8,
                        Asb + ch * 512);
        }
#pragma unroll
        for (int ch = wave; ch < BCH; ch += 4) {
            int e0 = ch * 512 + lane * 8;
            int kb = e0 / (BN * 32);
            int rem = e0 - kb * (BN * 32);
            int rr = rem >> 5;
            int gslot = ((rem & 31) >> 3) ^ ((rr >> 1) & 3);
            gload_lds16(Bbp + (size_t)(n0 + rr) * ldb + k0 + kb * 32 + gslot * 8,
                        Bsb + ch * 512);
        }
    };

    f32x4 acc[MI][NI];
#pragma unroll
    for (int i = 0; i < MI; ++i)
#pragma unroll
        for (int j = 0; j < NI; ++j) acc[i][j] = (f32x4){0.f, 0.f, 0.f, 0.f};

    stage(0, 0);
    asm volatile("s_waitcnt vmcnt(0)" ::: "memory");
    __syncthreads();

    int nsteps = K / BK;
    for (int t = 0; t < nsteps; ++t) {
        int cur = t & 1;
        if (t + 1 < nsteps) stage(cur ^ 1, (t + 1) * BK);
        const us* As = smem + cur * BUFSZ;
        const us* Bs = As + AE;
#pragma unroll
        for (int kb = 0; kb < BK / 32; ++kb) {
            const us* Abase = As + kb * BM * 32;
            const us* Bbase = Bs + kb * BN * 32;
            f16x8 a[MI], b[NI];
#pragma unroll
            for (int x = 0; x < MI; ++x) {
                int row = wr * WM + x * 16 + lr;
                a[x] = *reinterpret_cast<const f16x8*>(
                    &Abase[row * 32 + ((lg ^ ((row >> 1) & 3)) << 3)]);
            }
#pragma unroll
            for (int x = 0; x < NI; ++x) {
                int row = wc * WN + x * 16 + lr;
                b[x] = *reinterpret_cast<const f16x8*>(
                    &Bbase[row * 32 + ((lg ^ ((row >> 1) & 3)) << 3)]);
            }
#pragma unroll
            for (int mi = 0; mi < MI; ++mi)
#pragma unroll
                for (int ni = 0; ni < NI; ++ni)
                    acc[mi][ni] = __builtin_amdgcn_mfma_f32_16x16x32_f16(a[mi], b[ni], acc[mi][ni], 0, 0, 0);
        }
        asm volatile("s_waitcnt vmcnt(0)" ::: "memory");
        __syncthreads();
    }

    constexpr int SP = BN + 4;
    float* sst = reinterpret_cast<float*>(smem);
    constexpr int CSEG = BN / 8;
    int rl = tid >> 3;
    int cb = (tid & 7) * CSEG;
#pragma unroll
    for (int mi = 0; mi < MI; ++mi) {
        __syncthreads();
#pragma unroll
        for (int ni = 0; ni < NI; ++ni) {
#pragma unroll
            for (int r = 0; r < 4; ++r)
                sst[(wr * 16 + lg * 4 + r) * SP + wc * WN + ni * 16 + lr] = acc[mi][ni][r];
        }
        __syncthreads();
        int grow = m0 + (rl >> 4) * WM + mi * 16 + (rl & 15);
        float bs = 0.f;
        if constexpr (BIAS == 1) bs = bias[grow];
#pragma unroll
        for (int j = 0; j < CSEG / 4; ++j) {
            int col = n0 + cb + j * 4;
            float4 v = *reinterpret_cast<const float4*>(&sst[rl * SP + cb + j * 4]);
            if constexpr (BIAS == 1) { v.x += bs; v.y += bs; v.z += bs; v.w += bs; }
            if constexpr (BIAS == 2) {
                const float4 bv = *reinterpret_cast<const float4*>(&bias[col]);
                v.x += bv.x; v.y += bv.y; v.z += bv.z; v.w += bv.w;
            }
            size_t off = (size_t)bz * strideC + (size_t)grow * ldc + col;
            if constexpr (RESID) {
                const float4 rr4 = *reinterpret_cast<const float4*>(
                    &resid[(size_t)bz * strideR + (size_t)grow * ldc + col]);
                v.x += rr4.x; v.y += rr4.y; v.z += rr4.z; v.w += rr4.w;
            }
            if constexpr (EPI == 0) {
                *reinterpret_cast<float4*>(&((float*)out0)[off]) = v;
            } else {
                ull pk = (ull)f2h(v.x) | ((ull)f2h(v.y) << 16)
                       | ((ull)f2h(v.z) << 32) | ((ull)f2h(v.w) << 48);
                *reinterpret_cast<ull*>(&((us*)out0)[off]) = pk;
            }
        }
    }
}

// ------- fp16 MFMA GEMM (8-wave, 256x256, wave tile 128x64), dbuf + setprio ----
template <int SWZ>
__global__ __launch_bounds__(512) void mfma_gemm8w(
    const us* __restrict__ A, int lda, long long strideA,
    const us* __restrict__ B, int ldb, long long strideB,
    us* __restrict__ out0, int ldc, long long strideC,
    int K) {
    constexpr int BM = 256, BN = 256, BK = 32;
    constexpr int WM = 128, WN = 64;
    constexpr int MI = WM / 16, NI = WN / 16;  // 8, 4
    constexpr int AE = BM * BK, BE = BN * BK;
    constexpr int BUFSZ = AE + BE;             // 16384 elems = 32KB
    constexpr int ACH = AE / 512, BCH = BE / 512;
    __shared__ __attribute__((aligned(16))) us smem[2 * BUFSZ];

    int bz = blockIdx.z;
    const us* Ab = A + (size_t)bz * strideA;
    const us* Bbp = B + (size_t)bz * strideB;

    int bx = blockIdx.x, by = blockIdx.y;
    if constexpr (SWZ == 2) {
        int bid = blockIdx.x + gridDim.x * blockIdx.y;
        int xcd = bid & 7;
        int idx = bid >> 3;
        int rpr = gridDim.y >> 2;
        int cpr = gridDim.x >> 1;
        int row0 = (xcd >> 1) * rpr;
        int col0 = (xcd & 1) * cpr;
        by = row0 + idx / cpr;
        bx = col0 + idx % cpr;
    }
    int m0 = by * BM, n0 = bx * BN;
    int tid = threadIdx.x, wave = tid >> 6, lane = tid & 63;
    int wr = wave >> 2, wc = wave & 3;
    int lr = lane & 15, lg = lane >> 4;

    auto stage = [&](int buf, int k0) {
        us* Asb = smem + buf * BUFSZ;
        us* Bsb = Asb + AE;
#pragma unroll
        for (int ch = wave; ch < ACH; ch += 8) {
            int e0 = ch * 512 + lane * 8;
            int rr = e0 >> 5;
            int gslot = ((e0 & 31) >> 3) ^ ((rr >> 1) & 3);
            gload_lds16(Ab + (size_t)(m0 + rr) * lda + k0 + gslot * 8,
                        Asb + ch * 512);
        }
#pragma unroll
        for (int ch = wave; ch < BCH; ch += 8) {
            int e0 = ch * 512 + lane * 8;
            int rr = e0 >> 5;
            int gslot = ((e0 & 31) >> 3) ^ ((rr >> 1) & 3);
            gload_lds16(Bbp + (size_t)(n0 + rr) * ldb + k0 + gslot * 8,
                        Bsb + ch * 512);
        }
    };

    f32x4 acc[MI][NI];
#pragma unroll
    for (int i = 0; i < MI; ++i)
#pragma unroll
        for (int j = 0; j < NI; ++j) acc[i][j] = (f32x4){0.f, 0.f, 0.f, 0.f};

    stage(0, 0);
    asm volatile("s_waitcnt vmcnt(0)" ::: "memory");
    __syncthreads();

    int nsteps = K / BK;
    for (int t = 0; t < nsteps; ++t) {
        int cur = t & 1;
        if (t + 1 < nsteps) stage(cur ^ 1, (t + 1) * BK);
        const us* As = smem + cur * BUFSZ;
        const us* Bs = As + AE;
        f16x8 a[MI], b[NI];
#pragma unroll
        for (int x = 0; x < MI; ++x) {
            int row = wr * WM + x * 16 + lr;
            a[x] = *reinterpret_cast<const f16x8*>(
                &As[row * 32 + ((lg ^ ((row >> 1) & 3)) << 3)]);
        }
#pragma unroll
        for (int x = 0; x < NI; ++x) {
            int row = wc * WN + x * 16 + lr;
            b[x] = *reinterpret_cast<const f16x8*>(
                &Bs[row * 32 + ((lg ^ ((row >> 1) & 3)) << 3)]);
        }
        __builtin_amdgcn_s_setprio(1);         // T5: favor MFMA-issuing waves
#pragma unroll
        for (int mi = 0; mi < MI; ++mi)
#pragma unroll
            for (int ni = 0; ni < NI; ++ni)
                acc[mi][ni] = __builtin_amdgcn_mfma_f32_16x16x32_f16(a[mi], b[ni], acc[mi][ni], 0, 0, 0);
        __builtin_amdgcn_s_setprio(0);
        asm volatile("s_waitcnt vmcnt(0)" ::: "memory");
        __syncthreads();
    }

#pragma unroll
    for (int mi = 0; mi < MI; ++mi) {
        int row = m0 + wr * WM + mi * 16 + lg * 4;
#pragma unroll
        for (int ni = 0; ni < NI; ++ni) {
            int col = n0 + wc * WN + ni * 16 + lr;
#pragma unroll
            for (int r = 0; r < 4; ++r) {
                size_t off = (size_t)bz * strideC + (size_t)(row + r) * ldc + col;
                out0[off] = f2h(acc[mi][ni][r]);
            }
        }
    }
}

// ------- row softmax fp16 IN-PLACE (S row -> normalized P row) -------
__global__ __launch_bounds__(256) void softmax_kernel(us* __restrict__ S) {
    us* rowp = S + (size_t)blockIdx.y * ((size_t)Nn * Nn) + (size_t)blockIdx.x * Nn;
    f16x8* r8 = reinterpret_cast<f16x8*>(rowp);
    int t = threadIdx.x;
    float f[16];
    float mx = -1e30f;
#pragma unroll
    for (int j = 0; j < 2; ++j) {
        f16x8 v = r8[t + 256 * j];
#pragma unroll
        for (int e = 0; e < 8; ++e) {
            f[j * 8 + e] = (float)v[e];
            mx = fmaxf(mx, f[j * 8 + e]);
        }
    }
    for (int off = 32; off; off >>= 1) mx = fmaxf(mx, __shfl_down(mx, off));
    __shared__ float redm[4], reds[4];
    int wid = t >> 6;
    if ((t & 63) == 0) redm[wid] = mx;
    __syncthreads();
    mx = fmaxf(fmaxf(redm[0], redm[1]), fmaxf(redm[2], redm[3]));
    float s = 0.f;
#pragma unroll
    for (int j = 0; j < 16; ++j) {
        f[j] = __expf(f[j] - mx);
        s += f[j];
    }
    for (int off = 32; off; off >>= 1) s += __shfl_down(s, off);
    if ((t & 63) == 0) reds[wid] = s;
    __syncthreads();
    s = reds[0] + reds[1] + reds[2] + reds[3];
    float inv = 1.f / s;
#pragma unroll
    for (int j = 0; j < 2; ++j) {
        f16x8 o;
#pragma unroll
        for (int e = 0; e < 8; ++e) o[e] = (_Float16)(f[j * 8 + e] * inv);
        r8[t + 256 * j] = o;
    }
}

extern "C" void kernel_launch(void* const* d_in, const int* in_sizes, int n_in,
                              void* d_out, int out_size, void* d_ws, size_t ws_size,
                              hipStream_t stream) {
    const float* content = (const float*)d_in[0];
    const float* style   = (const float*)d_in[1];
    const float* f_w = (const float*)d_in[2];
    const float* f_b = (const float*)d_in[3];
    const float* g_w = (const float*)d_in[4];
    const float* g_b = (const float*)d_in[5];
    const float* h_w = (const float*)d_in[6];
    const float* h_b = (const float*)d_in[7];
    const float* o_w = (const float*)d_in[8];
    const float* o_b = (const float*)d_in[9];
    float* out = (float*)d_out;
    char* ws = (char*)d_ws;

    const size_t PB   = (size_t)Cc * Nn;
    const size_t TEN  = PB * Bb;
    const size_t SMAT = (size_t)Nn * Nn;

    us* FT  = (us*)ws;
    us* GT  = FT + TEN;
    us* Hbf = GT + TEN;
    us* OT  = Hbf + TEN;
    us* fwh = OT + TEN;
    us* gwh = fwh + Cc * Cc;
    us* hwb = gwh + Cc * Cc;
    us* owb = hwb + Cc * Cc;
    float* meanC = (float*)(owb + Cc * Cc);
    float* rstdC = meanC + Bb * Cc;
    float* meanS = rstdC + Bb * Cc;
    float* rstdS = meanS + Bb * Cc;
    us* CN = (us*)(rstdS + Bb * Cc);
    us* SN = CN + TEN;
    us* SR = SN + TEN;
    us* S4 = CN;   // overlays dead CN/SN/SR after convs

    stats2_kernel<<<2 * Bb * Cc, 256, 0, stream>>>(content, style,
                                                   meanC, rstdC, meanS, rstdS);

    dim3 pgrid(Nn / 64, Cc / 64, Bb);
    pack_T<<<pgrid, 256, 0, stream>>>(content, meanC, rstdC, CN);
    pack_style<<<pgrid, 256, 0, stream>>>(style, meanS, rstdS, SN, SR);
    pack_w<<<(Cc * Cc + 255) / 256, 256, 0, stream>>>(f_w, g_w, h_w, o_w,
                                                      fwh, gwh, hwb, owb);

    // F^T[q][c'] = sum_c CN[q][c] f_w[c'][c] + f_b[c']
    mfma_gemm<1, 2, false, 64, 64, 64, 1><<<dim3(Cc / 64, Nn / 64, Bb), 256, 0, stream>>>(
        CN, Cc, (long long)PB, fwh, Cc, 0,
        FT, Cc, (long long)PB, f_b, nullptr, 0, Cc);
    // G^T likewise
    mfma_gemm<1, 2, false, 64, 64, 64, 1><<<dim3(Cc / 64, Nn / 64, Bb), 256, 0, stream>>>(
        SN, Cc, (long long)PB, gwh, Cc, 0,
        GT, Cc, (long long)PB, g_b, nullptr, 0, Cc);
    // H[c'][s]
    mfma_gemm<1, 1, false, 64, 64, 64, 1><<<dim3(Nn / 64, Cc / 64, Bb), 256, 0, stream>>>(
        hwb, Cc, 0, SR, Cc, (long long)PB,
        Hbf, Nn, (long long)PB, h_b, nullptr, 0, Cc);

    // S[q][s] = F^T . G^T  (M=N=4096,K=512): 8-wave 256x256, wave tile 128x64
    mfma_gemm8w<2><<<dim3(Nn / 256, Nn / 256, Bb), 512, 0, stream>>>(
        FT, Cc, (long long)PB, GT, Cc, (long long)PB,
        S4, Nn, (long long)SMAT, Cc);
    softmax_kernel<<<dim3(Nn, Bb), 256, 0, stream>>>(S4);
    // O^T[q][c'] = P . H  (M=4096,N=512,K=4096)
    mfma_gemm<1, 0, false, 128, 128, 64, 2><<<dim3(Cc / 128, Nn / 128, Bb), 256, 0, stream>>>(
        S4, Nn, (long long)SMAT, Hbf, Nn, (long long)PB,
        OT, Cc, (long long)PB, nullptr, nullptr, 0, Nn);

    // out = o_w . O^T + o_b + content
    mfma_gemm<0, 1, true, 64, 64, 64, 1><<<dim3(Nn / 64, Cc / 64, Bb), 256, 0, stream>>>(
        owb, Cc, 0, OT, Cc, (long long)PB,
        out, Nn, (long long)PB, o_b, content, (long long)PB, Cc);
}

// Round 23
// 320.052 us; speedup vs baseline: 1.0640x; 1.0246x over previous
//
#include <hip/hip_runtime.h>

constexpr int Cc = 512;
constexpr int Nn = 4096;   // 64*64
constexpr int Bb = 4;
#define EPS 1e-5f

using f16x8 = __attribute__((ext_vector_type(8))) _Float16;
using f32x4 = __attribute__((ext_vector_type(4))) float;
typedef unsigned short us;
typedef unsigned long long ull;

__device__ __forceinline__ us f2h(float f) {
    union { _Float16 h; us u; } v; v.h = (_Float16)f;
    return v.u;
}
__device__ __forceinline__ void gload_lds16(const void* g, void* l) {
    __builtin_amdgcn_global_load_lds(
        (const __attribute__((address_space(1))) void*)g,
        (__attribute__((address_space(3))) void*)l, 16, 0, 0);
}

// ---- stats for BOTH tensors in one launch: per (b,c) mean & rstd (ddof=1) ----
__global__ __launch_bounds__(256) void stats2_kernel(const float* __restrict__ x0,
                                                     const float* __restrict__ x1,
                                                     float* __restrict__ mean0,
                                                     float* __restrict__ rstd0,
                                                     float* __restrict__ mean1,
                                                     float* __restrict__ rstd1) {
    int bc = blockIdx.x;
    const float* row;
    float *mean, *rstd;
    int idx;
    if (bc < Bb * Cc) { idx = bc; row = x0 + (size_t)idx * Nn; mean = mean0; rstd = rstd0; }
    else              { idx = bc - Bb * Cc; row = x1 + (size_t)idx * Nn; mean = mean1; rstd = rstd1; }
    float s = 0.f, sq = 0.f;
    for (int i = threadIdx.x * 4; i < Nn; i += 256 * 4) {
        float4 v = *reinterpret_cast<const float4*>(row + i);
        s  += v.x + v.y + v.z + v.w;
        sq += v.x*v.x + v.y*v.y + v.z*v.z + v.w*v.w;
    }
    for (int off = 32; off; off >>= 1) {
        s  += __shfl_down(s, off);
        sq += __shfl_down(sq, off);
    }
    __shared__ float ls[4], lsq[4];
    int wid = threadIdx.x >> 6;
    if ((threadIdx.x & 63) == 0) { ls[wid] = s; lsq[wid] = sq; }
    __syncthreads();
    if (threadIdx.x == 0) {
        float S  = ls[0] + ls[1] + ls[2] + ls[3];
        float SQ = lsq[0] + lsq[1] + lsq[2] + lsq[3];
        float m  = S / (float)Nn;
        float var = (SQ - S * m) / (float)(Nn - 1);
        mean[idx] = m;
        rstd[idx] = rsqrtf(var + EPS);
    }
}

// ---- fused packs: z<Bb: content -> CN (normed). z>=Bb: style -> SR raw + SN normed.
// All paths fp32 [b][c][n] -> fp16 transposed [b][n][c]; arithmetic identical to
// the previous separate kernels ((v-mean)*rstd at write time).
__global__ __launch_bounds__(256) void pack_all(const float* __restrict__ content,
                                                const float* __restrict__ style,
                                                const float* __restrict__ meanC,
                                                const float* __restrict__ rstdC,
                                                const float* __restrict__ meanS,
                                                const float* __restrict__ rstdS,
                                                us* __restrict__ CN,
                                                us* __restrict__ SN,
                                                us* __restrict__ SR) {
    int z = blockIdx.z;
    int b = z & (Bb - 1);
    bool sty = z >= Bb;
    int n0 = blockIdx.x * 64, c0 = blockIdx.y * 64;
    __shared__ float tile[64][65];
    const float* Xb = (sty ? style : content) + (size_t)b * Cc * Nn;
    for (int i = threadIdx.x; i < 64 * 64; i += 256) {
        int c = i >> 6, n = i & 63;
        tile[c][n] = Xb[(size_t)(c0 + c) * Nn + n0 + n];   // raw
    }
    __syncthreads();
    if (!sty) {
        us* Pb = CN + (size_t)b * Nn * Cc;
        for (int i = threadIdx.x; i < 64 * 64; i += 256) {
            int n = i >> 6, c = i & 63;
            int cg = b * Cc + c0 + c;
            Pb[(size_t)(n0 + n) * Cc + c0 + c] =
                f2h((tile[c][n] - meanC[cg]) * rstdC[cg]);
        }
    } else {
        us* Nb = SN + (size_t)b * Nn * Cc;
        us* Rb = SR + (size_t)b * Nn * Cc;
        for (int i = threadIdx.x; i < 64 * 64; i += 256) {
            int n = i >> 6, c = i & 63;
            float raw = tile[c][n];
            int cg = b * Cc + c0 + c;
            size_t off = (size_t)(n0 + n) * Cc + c0 + c;
            Rb[off] = f2h(raw);
            Nb[off] = f2h((raw - meanS[cg]) * rstdS[cg]);
        }
    }
}

// ------ pack the four 512x512 weights to fp16 ------
__global__ __launch_bounds__(256) void pack_w(const float* __restrict__ fw, const float* __restrict__ gw,
                                              const float* __restrict__ hw, const float* __restrict__ ow,
                                              us* __restrict__ fo, us* __restrict__ go,
                                              us* __restrict__ ho, us* __restrict__ oo) {
    int i = blockIdx.x * 256 + threadIdx.x;
    if (i >= Cc * Cc) return;
    fo[i] = f2h(fw[i]);
    go[i] = f2h(gw[i]);
    ho[i] = f2h(hw[i]);
    oo[i] = f2h(ow[i]);
}

// ------------- fp16 MFMA GEMM (4-wave): C[m][n'] = sum_k A[m][k]*B[n'][k] ------
// Double-buffered LDS, XOR swizzle, LDS-staged epilogue (r17/r20 structure).
// B2/bias2 non-null => fused dual-problem launch: z >= gridDim.z/2 uses B2/bias2
// (A and out index linearly over z; their slabs are contiguous).
template <int EPI, int BIAS, bool RESID, int BM, int BN, int BK, int SWZ>
__global__ __launch_bounds__(256) void mfma_gemm(
    const us* __restrict__ A, int lda, long long strideA,
    const us* __restrict__ B, const us* __restrict__ B2, int ldb, long long strideB,
    void* __restrict__ out0, int ldc, long long strideC,
    const float* __restrict__ bias, const float* __restrict__ bias2,
    const float* __restrict__ resid, long long strideR,
    int K) {
    constexpr int WM = BM / 2, WN = BN / 2;
    constexpr int MI = WM / 16, NI = WN / 16;
    constexpr int AE = BM * BK, BE = BN * BK;
    constexpr int BUFSZ = AE + BE;
    constexpr int ACH = AE / 512, BCH = BE / 512;
    __shared__ __attribute__((aligned(16))) us smem[2 * BUFSZ];

    int bz = blockIdx.z;
    const us* Ab = A + (size_t)bz * strideA;
    const float* biasp = bias;
    const us* Bbp;
    if (B2 != nullptr) {
        int half = gridDim.z >> 1;
        if (bz >= half) { Bbp = B2 + (size_t)(bz - half) * strideB; biasp = bias2; }
        else            { Bbp = B + (size_t)bz * strideB; }
    } else {
        Bbp = B + (size_t)bz * strideB;
    }

    int bx = blockIdx.x, by = blockIdx.y;
    if constexpr (SWZ == 1) {
        int nwg = gridDim.x * gridDim.y;
        int bid = blockIdx.x + gridDim.x * blockIdx.y;
        int cpx = nwg >> 3;
        int swz = (bid & 7) * cpx + (bid >> 3);
        bx = swz % gridDim.x;
        by = swz / gridDim.x;
    } else if constexpr (SWZ == 2) {
        int bid = blockIdx.x + gridDim.x * blockIdx.y;
        int xcd = bid & 7;
        int idx = bid >> 3;
        int rpr = gridDim.y >> 2;
        int cpr = gridDim.x >> 1;
        int row0 = (xcd >> 1) * rpr;
        int col0 = (xcd & 1) * cpr;
        by = row0 + idx / cpr;
        bx = col0 + idx % cpr;
    }
    int m0 = by * BM, n0 = bx * BN;
    int tid = threadIdx.x, wave = tid >> 6, lane = tid & 63;
    int wr = wave >> 1, wc = wave & 1;
    int lr = lane & 15, lg = lane >> 4;

    auto stage = [&](int buf, int k0) {
        us* Asb = smem + buf * BUFSZ;
        us* Bsb = Asb + AE;
#pragma unroll
        for (int ch = wave; ch < ACH; ch += 4) {
            int e0 = ch * 512 + lane * 8;
            int kb = e0 / (BM * 32);
            int rem = e0 - kb * (BM * 32);
            int rr = rem >> 5;
            int gslot = ((rem & 31) >> 3) ^ ((rr >> 1) & 3);
            gload_lds16(Ab + (size_t)(m0 + rr) * lda + k0 + kb * 32 + gslot * 8,
                        Asb + ch * 512);
        }
#pragma unroll
        for (int ch = wave; ch < BCH; ch += 4) {
            int e0 = ch * 512 + lane * 8;
            int kb = e0 / (BN * 32);
            int rem = e0 - kb * (BN * 32);
            int rr = rem >> 5;
            int gslot = ((rem & 31) >> 3) ^ ((rr >> 1) & 3);
            gload_lds16(Bbp + (size_t)(n0 + rr) * ldb + k0 + kb * 32 + gslot * 8,
                        Bsb + ch * 512);
        }
    };

    f32x4 acc[MI][NI];
#pragma unroll
    for (int i = 0; i < MI; ++i)
#pragma unroll
        for (int j = 0; j < NI; ++j) acc[i][j] = (f32x4){0.f, 0.f, 0.f, 0.f};

    stage(0, 0);
    asm volatile("s_waitcnt vmcnt(0)" ::: "memory");
    __syncthreads();

    int nsteps = K / BK;
    for (int t = 0; t < nsteps; ++t) {
        int cur = t & 1;
        if (t + 1 < nsteps) stage(cur ^ 1, (t + 1) * BK);
        const us* As = smem + cur * BUFSZ;
        const us* Bs = As + AE;
#pragma unroll
        for (int kb = 0; kb < BK / 32; ++kb) {
            const us* Abase = As + kb * BM * 32;
            const us* Bbase = Bs + kb * BN * 32;
            f16x8 a[MI], b[NI];
#pragma unroll
            for (int x = 0; x < MI; ++x) {
                int row = wr * WM + x * 16 + lr;
                a[x] = *reinterpret_cast<const f16x8*>(
                    &Abase[row * 32 + ((lg ^ ((row >> 1) & 3)) << 3)]);
            }
#pragma unroll
            for (int x = 0; x < NI; ++x) {
                int row = wc * WN + x * 16 + lr;
                b[x] = *reinterpret_cast<const f16x8*>(
                    &Bbase[row * 32 + ((lg ^ ((row >> 1) & 3)) << 3)]);
            }
#pragma unroll
            for (int mi = 0; mi < MI; ++mi)
#pragma unroll
                for (int ni = 0; ni < NI; ++ni)
                    acc[mi][ni] = __builtin_amdgcn_mfma_f32_16x16x32_f16(a[mi], b[ni], acc[mi][ni], 0, 0, 0);
        }
        asm volatile("s_waitcnt vmcnt(0)" ::: "memory");
        __syncthreads();
    }

    constexpr int SP = BN + 4;
    float* sst = reinterpret_cast<float*>(smem);
    constexpr int CSEG = BN / 8;
    int rl = tid >> 3;
    int cb = (tid & 7) * CSEG;
#pragma unroll
    for (int mi = 0; mi < MI; ++mi) {
        __syncthreads();
#pragma unroll
        for (int ni = 0; ni < NI; ++ni) {
#pragma unroll
            for (int r = 0; r < 4; ++r)
                sst[(wr * 16 + lg * 4 + r) * SP + wc * WN + ni * 16 + lr] = acc[mi][ni][r];
        }
        __syncthreads();
        int grow = m0 + (rl >> 4) * WM + mi * 16 + (rl & 15);
        float bs = 0.f;
        if constexpr (BIAS == 1) bs = biasp[grow];
#pragma unroll
        for (int j = 0; j < CSEG / 4; ++j) {
            int col = n0 + cb + j * 4;
            float4 v = *reinterpret_cast<const float4*>(&sst[rl * SP + cb + j * 4]);
            if constexpr (BIAS == 1) { v.x += bs; v.y += bs; v.z += bs; v.w += bs; }
            if constexpr (BIAS == 2) {
                const float4 bv = *reinterpret_cast<const float4*>(&biasp[col]);
                v.x += bv.x; v.y += bv.y; v.z += bv.z; v.w += bv.w;
            }
            size_t off = (size_t)bz * strideC + (size_t)grow * ldc + col;
            if constexpr (RESID) {
                const float4 rr4 = *reinterpret_cast<const float4*>(
                    &resid[(size_t)bz * strideR + (size_t)grow * ldc + col]);
                v.x += rr4.x; v.y += rr4.y; v.z += rr4.z; v.w += rr4.w;
            }
            if constexpr (EPI == 0) {
                *reinterpret_cast<float4*>(&((float*)out0)[off]) = v;
            } else {
                ull pk = (ull)f2h(v.x) | ((ull)f2h(v.y) << 16)
                       | ((ull)f2h(v.z) << 32) | ((ull)f2h(v.w) << 48);
                *reinterpret_cast<ull*>(&((us*)out0)[off]) = pk;
            }
        }
    }
}

// ------- fp16 MFMA GEMM (8-wave, 256x256, wave tile 128x64), dbuf (r20 exact) ----
template <int SWZ>
__global__ __launch_bounds__(512) void mfma_gemm8w(
    const us* __restrict__ A, int lda, long long strideA,
    const us* __restrict__ B, int ldb, long long strideB,
    us* __restrict__ out0, int ldc, long long strideC,
    int K) {
    constexpr int BM = 256, BN = 256, BK = 32;
    constexpr int WM = 128, WN = 64;
    constexpr int MI = WM / 16, NI = WN / 16;  // 8, 4
    constexpr int AE = BM * BK, BE = BN * BK;
    constexpr int BUFSZ = AE + BE;             // 16384 elems = 32KB
    constexpr int ACH = AE / 512, BCH = BE / 512;
    __shared__ __attribute__((aligned(16))) us smem[2 * BUFSZ];

    int bz = blockIdx.z;
    const us* Ab = A + (size_t)bz * strideA;
    const us* Bbp = B + (size_t)bz * strideB;

    int bx = blockIdx.x, by = blockIdx.y;
    if constexpr (SWZ == 2) {
        int bid = blockIdx.x + gridDim.x * blockIdx.y;
        int xcd = bid & 7;
        int idx = bid >> 3;
        int rpr = gridDim.y >> 2;
        int cpr = gridDim.x >> 1;
        int row0 = (xcd >> 1) * rpr;
        int col0 = (xcd & 1) * cpr;
        by = row0 + idx / cpr;
        bx = col0 + idx % cpr;
    }
    int m0 = by * BM, n0 = bx * BN;
    int tid = threadIdx.x, wave = tid >> 6, lane = tid & 63;
    int wr = wave >> 2, wc = wave & 3;
    int lr = lane & 15, lg = lane >> 4;

    auto stage = [&](int buf, int k0) {
        us* Asb = smem + buf * BUFSZ;
        us* Bsb = Asb + AE;
#pragma unroll
        for (int ch = wave; ch < ACH; ch += 8) {
            int e0 = ch * 512 + lane * 8;
            int rr = e0 >> 5;
            int gslot = ((e0 & 31) >> 3) ^ ((rr >> 1) & 3);
            gload_lds16(Ab + (size_t)(m0 + rr) * lda + k0 + gslot * 8,
                        Asb + ch * 512);
        }
#pragma unroll
        for (int ch = wave; ch < BCH; ch += 8) {
            int e0 = ch * 512 + lane * 8;
            int rr = e0 >> 5;
            int gslot = ((e0 & 31) >> 3) ^ ((rr >> 1) & 3);
            gload_lds16(Bbp + (size_t)(n0 + rr) * ldb + k0 + gslot * 8,
                        Bsb + ch * 512);
        }
    };

    f32x4 acc[MI][NI];
#pragma unroll
    for (int i = 0; i < MI; ++i)
#pragma unroll
        for (int j = 0; j < NI; ++j) acc[i][j] = (f32x4){0.f, 0.f, 0.f, 0.f};

    stage(0, 0);
    asm volatile("s_waitcnt vmcnt(0)" ::: "memory");
    __syncthreads();

    int nsteps = K / BK;
    for (int t = 0; t < nsteps; ++t) {
        int cur = t & 1;
        if (t + 1 < nsteps) stage(cur ^ 1, (t + 1) * BK);
        const us* As = smem + cur * BUFSZ;
        const us* Bs = As + AE;
        f16x8 a[MI], b[NI];
#pragma unroll
        for (int x = 0; x < MI; ++x) {
            int row = wr * WM + x * 16 + lr;
            a[x] = *reinterpret_cast<const f16x8*>(
                &As[row * 32 + ((lg ^ ((row >> 1) & 3)) << 3)]);
        }
#pragma unroll
        for (int x = 0; x < NI; ++x) {
            int row = wc * WN + x * 16 + lr;
            b[x] = *reinterpret_cast<const f16x8*>(
                &Bs[row * 32 + ((lg ^ ((row >> 1) & 3)) << 3)]);
        }
#pragma unroll
        for (int mi = 0; mi < MI; ++mi)
#pragma unroll
            for (int ni = 0; ni < NI; ++ni)
                acc[mi][ni] = __builtin_amdgcn_mfma_f32_16x16x32_f16(a[mi], b[ni], acc[mi][ni], 0, 0, 0);
        asm volatile("s_waitcnt vmcnt(0)" ::: "memory");
        __syncthreads();
    }

#pragma unroll
    for (int mi = 0; mi < MI; ++mi) {
        int row = m0 + wr * WM + mi * 16 + lg * 4;
#pragma unroll
        for (int ni = 0; ni < NI; ++ni) {
            int col = n0 + wc * WN + ni * 16 + lr;
#pragma unroll
            for (int r = 0; r < 4; ++r) {
                size_t off = (size_t)bz * strideC + (size_t)(row + r) * ldc + col;
                out0[off] = f2h(acc[mi][ni][r]);
            }
        }
    }
}

// ------- row softmax fp16 IN-PLACE (S row -> normalized P row) -------
__global__ __launch_bounds__(256) void softmax_kernel(us* __restrict__ S) {
    us* rowp = S + (size_t)blockIdx.y * ((size_t)Nn * Nn) + (size_t)blockIdx.x * Nn;
    f16x8* r8 = reinterpret_cast<f16x8*>(rowp);
    int t = threadIdx.x;
    float f[16];
    float mx = -1e30f;
#pragma unroll
    for (int j = 0; j < 2; ++j) {
        f16x8 v = r8[t + 256 * j];
#pragma unroll
        for (int e = 0; e < 8; ++e) {
            f[j * 8 + e] = (float)v[e];
            mx = fmaxf(mx, f[j * 8 + e]);
        }
    }
    for (int off = 32; off; off >>= 1) mx = fmaxf(mx, __shfl_down(mx, off));
    __shared__ float redm[4], reds[4];
    int wid = t >> 6;
    if ((t & 63) == 0) redm[wid] = mx;
    __syncthreads();
    mx = fmaxf(fmaxf(redm[0], redm[1]), fmaxf(redm[2], redm[3]));
    float s = 0.f;
#pragma unroll
    for (int j = 0; j < 16; ++j) {
        f[j] = __expf(f[j] - mx);
        s += f[j];
    }
    for (int off = 32; off; off >>= 1) s += __shfl_down(s, off);
    if ((t & 63) == 0) reds[wid] = s;
    __syncthreads();
    s = reds[0] + reds[1] + reds[2] + reds[3];
    float inv = 1.f / s;
#pragma unroll
    for (int j = 0; j < 2; ++j) {
        f16x8 o;
#pragma unroll
        for (int e = 0; e < 8; ++e) o[e] = (_Float16)(f[j * 8 + e] * inv);
        r8[t + 256 * j] = o;
    }
}

extern "C" void kernel_launch(void* const* d_in, const int* in_sizes, int n_in,
                              void* d_out, int out_size, void* d_ws, size_t ws_size,
                              hipStream_t stream) {
    const float* content = (const float*)d_in[0];
    const float* style   = (const float*)d_in[1];
    const float* f_w = (const float*)d_in[2];
    const float* f_b = (const float*)d_in[3];
    const float* g_w = (const float*)d_in[4];
    const float* g_b = (const float*)d_in[5];
    const float* h_w = (const float*)d_in[6];
    const float* h_b = (const float*)d_in[7];
    const float* o_w = (const float*)d_in[8];
    const float* o_b = (const float*)d_in[9];
    float* out = (float*)d_out;
    char* ws = (char*)d_ws;

    const size_t PB   = (size_t)Cc * Nn;
    const size_t TEN  = PB * Bb;
    const size_t SMAT = (size_t)Nn * Nn;

    us* FT  = (us*)ws;
    us* GT  = FT + TEN;                        // contiguous after FT (fused F/G out)
    us* Hbf = GT + TEN;
    us* OT  = Hbf + TEN;
    us* fwh = OT + TEN;
    us* gwh = fwh + Cc * Cc;
    us* hwb = gwh + Cc * Cc;
    us* owb = hwb + Cc * Cc;
    float* meanC = (float*)(owb + Cc * Cc);
    float* rstdC = meanC + Bb * Cc;
    float* meanS = rstdC + Bb * Cc;
    float* rstdS = meanS + Bb * Cc;
    us* CN = (us*)(rstdS + Bb * Cc);
    us* SN = CN + TEN;                         // contiguous after CN (fused F/G in)
    us* SR = SN + TEN;
    us* S4 = CN;   // overlays dead CN/SN/SR after convs

    stats2_kernel<<<2 * Bb * Cc, 256, 0, stream>>>(content, style,
                                                   meanC, rstdC, meanS, rstdS);

    pack_all<<<dim3(Nn / 64, Cc / 64, 2 * Bb), 256, 0, stream>>>(
        content, style, meanC, rstdC, meanS, rstdS, CN, SN, SR);
    pack_w<<<(Cc * Cc + 255) / 256, 256, 0, stream>>>(f_w, g_w, h_w, o_w,
                                                      fwh, gwh, hwb, owb);

    // FUSED F+G convs: z<4 -> F^T = CN.f_w + f_b; z>=4 -> G^T = SN.g_w + g_b
    // (CN/SN and FT/GT are contiguous slabs; B/bias select by z-half.)
    mfma_gemm<1, 2, false, 64, 64, 64, 1><<<dim3(Cc / 64, Nn / 64, 2 * Bb), 256, 0, stream>>>(
        CN, Cc, (long long)PB, fwh, gwh, Cc, 0,
        FT, Cc, (long long)PB, f_b, g_b, nullptr, 0, Cc);
    // H[c'][s] = sum_c h_w[c'][c] SR[s][c] + h_b[c']
    mfma_gemm<1, 1, false, 64, 64, 64, 1><<<dim3(Nn / 64, Cc / 64, Bb), 256, 0, stream>>>(
        hwb, Cc, 0, SR, nullptr, Cc, (long long)PB,
        Hbf, Nn, (long long)PB, h_b, nullptr, nullptr, 0, Cc);

    // S[q][s] = F^T . G^T  (M=N=4096,K=512): 8-wave 256x256, wave tile 128x64
    mfma_gemm8w<2><<<dim3(Nn / 256, Nn / 256, Bb), 512, 0, stream>>>(
        FT, Cc, (long long)PB, GT, Cc, (long long)PB,
        S4, Nn, (long long)SMAT, Cc);
    softmax_kernel<<<dim3(Nn, Bb), 256, 0, stream>>>(S4);
    // O^T[q][c'] = P . H  (M=4096,N=512,K=4096)
    mfma_gemm<1, 0, false, 128, 128, 64, 2><<<dim3(Cc / 128, Nn / 128, Bb), 256, 0, stream>>>(
        S4, Nn, (long long)SMAT, Hbf, nullptr, Nn, (long long)PB,
        OT, Cc, (long long)PB, nullptr, nullptr, nullptr, 0, Nn);

    // out = o_w . O^T + o_b + content
    mfma_gemm<0, 1, true, 64, 64, 64, 1><<<dim3(Nn / 64, Cc / 64, Bb), 256, 0, stream>>>(
        owb, Cc, 0, OT, nullptr, Cc, (long long)PB,
        out, Nn, (long long)PB, o_b, nullptr, content, (long long)PB, Cc);
}

// Round 24
// 317.755 us; speedup vs baseline: 1.0717x; 1.0072x over previous
//
#include <hip/hip_runtime.h>

constexpr int Cc = 512;
constexpr int Nn = 4096;   // 64*64
constexpr int Bb = 4;
#define EPS 1e-5f

using f16x8 = __attribute__((ext_vector_type(8))) _Float16;
using f32x4 = __attribute__((ext_vector_type(4))) float;
typedef unsigned short us;
typedef unsigned long long ull;

__device__ __forceinline__ us f2h(float f) {
    union { _Float16 h; us u; } v; v.h = (_Float16)f;
    return v.u;
}
__device__ __forceinline__ void gload_lds16(const void* g, void* l) {
    __builtin_amdgcn_global_load_lds(
        (const __attribute__((address_space(1))) void*)g,
        (__attribute__((address_space(3))) void*)l, 16, 0, 0);
}

// ---- stats for BOTH tensors in one launch: per (b,c) mean & rstd (ddof=1) ----
__global__ __launch_bounds__(256) void stats2_kernel(const float* __restrict__ x0,
                                                     const float* __restrict__ x1,
                                                     float* __restrict__ mean0,
                                                     float* __restrict__ rstd0,
                                                     float* __restrict__ mean1,
                                                     float* __restrict__ rstd1) {
    int bc = blockIdx.x;
    const float* row;
    float *mean, *rstd;
    int idx;
    if (bc < Bb * Cc) { idx = bc; row = x0 + (size_t)idx * Nn; mean = mean0; rstd = rstd0; }
    else              { idx = bc - Bb * Cc; row = x1 + (size_t)idx * Nn; mean = mean1; rstd = rstd1; }
    float s = 0.f, sq = 0.f;
    for (int i = threadIdx.x * 4; i < Nn; i += 256 * 4) {
        float4 v = *reinterpret_cast<const float4*>(row + i);
        s  += v.x + v.y + v.z + v.w;
        sq += v.x*v.x + v.y*v.y + v.z*v.z + v.w*v.w;
    }
    for (int off = 32; off; off >>= 1) {
        s  += __shfl_down(s, off);
        sq += __shfl_down(sq, off);
    }
    __shared__ float ls[4], lsq[4];
    int wid = threadIdx.x >> 6;
    if ((threadIdx.x & 63) == 0) { ls[wid] = s; lsq[wid] = sq; }
    __syncthreads();
    if (threadIdx.x == 0) {
        float S  = ls[0] + ls[1] + ls[2] + ls[3];
        float SQ = lsq[0] + lsq[1] + lsq[2] + lsq[3];
        float m  = S / (float)Nn;
        float var = (SQ - S * m) / (float)(Nn - 1);
        mean[idx] = m;
        rstd[idx] = rsqrtf(var + EPS);
    }
}

// ---- fused packs: z<Bb: content -> CN (normed). z>=Bb: style -> SR raw + SN normed.
__global__ __launch_bounds__(256) void pack_all(const float* __restrict__ content,
                                                const float* __restrict__ style,
                                                const float* __restrict__ meanC,
                                                const float* __restrict__ rstdC,
                                                const float* __restrict__ meanS,
                                                const float* __restrict__ rstdS,
                                                us* __restrict__ CN,
                                                us* __restrict__ SN,
                                                us* __restrict__ SR) {
    int z = blockIdx.z;
    int b = z & (Bb - 1);
    bool sty = z >= Bb;
    int n0 = blockIdx.x * 64, c0 = blockIdx.y * 64;
    __shared__ float tile[64][65];
    const float* Xb = (sty ? style : content) + (size_t)b * Cc * Nn;
    for (int i = threadIdx.x; i < 64 * 64; i += 256) {
        int c = i >> 6, n = i & 63;
        tile[c][n] = Xb[(size_t)(c0 + c) * Nn + n0 + n];   // raw
    }
    __syncthreads();
    if (!sty) {
        us* Pb = CN + (size_t)b * Nn * Cc;
        for (int i = threadIdx.x; i < 64 * 64; i += 256) {
            int n = i >> 6, c = i & 63;
            int cg = b * Cc + c0 + c;
            Pb[(size_t)(n0 + n) * Cc + c0 + c] =
                f2h((tile[c][n] - meanC[cg]) * rstdC[cg]);
        }
    } else {
        us* Nb = SN + (size_t)b * Nn * Cc;
        us* Rb = SR + (size_t)b * Nn * Cc;
        for (int i = threadIdx.x; i < 64 * 64; i += 256) {
            int n = i >> 6, c = i & 63;
            float raw = tile[c][n];
            int cg = b * Cc + c0 + c;
            size_t off = (size_t)(n0 + n) * Cc + c0 + c;
            Rb[off] = f2h(raw);
            Nb[off] = f2h((raw - meanS[cg]) * rstdS[cg]);
        }
    }
}

// ------ pack the four 512x512 weights to fp16 ------
__global__ __launch_bounds__(256) void pack_w(const float* __restrict__ fw, const float* __restrict__ gw,
                                              const float* __restrict__ hw, const float* __restrict__ ow,
                                              us* __restrict__ fo, us* __restrict__ go,
                                              us* __restrict__ ho, us* __restrict__ oo) {
    int i = blockIdx.x * 256 + threadIdx.x;
    if (i >= Cc * Cc) return;
    fo[i] = f2h(fw[i]);
    go[i] = f2h(gw[i]);
    ho[i] = f2h(hw[i]);
    oo[i] = f2h(ow[i]);
}

// ------------- fp16 MFMA GEMM (4-wave): C[m][n'] = sum_k A[m][k]*B[n'][k] ------
// Double-buffered LDS, XOR swizzle, LDS-staged epilogue (r17/r20 structure).
// B2/bias2 non-null => fused dual-problem launch (z-half selects B/bias).
template <int EPI, int BIAS, bool RESID, int BM, int BN, int BK, int SWZ>
__global__ __launch_bounds__(256) void mfma_gemm(
    const us* __restrict__ A, int lda, long long strideA,
    const us* __restrict__ B, const us* __restrict__ B2, int ldb, long long strideB,
    void* __restrict__ out0, int ldc, long long strideC,
    const float* __restrict__ bias, const float* __restrict__ bias2,
    const float* __restrict__ resid, long long strideR,
    int K) {
    constexpr int WM = BM / 2, WN = BN / 2;
    constexpr int MI = WM / 16, NI = WN / 16;
    constexpr int AE = BM * BK, BE = BN * BK;
    constexpr int BUFSZ = AE + BE;
    constexpr int ACH = AE / 512, BCH = BE / 512;
    __shared__ __attribute__((aligned(16))) us smem[2 * BUFSZ];

    int bz = blockIdx.z;
    const us* Ab = A + (size_t)bz * strideA;
    const float* biasp = bias;
    const us* Bbp;
    if (B2 != nullptr) {
        int half = gridDim.z >> 1;
        if (bz >= half) { Bbp = B2 + (size_t)(bz - half) * strideB; biasp = bias2; }
        else            { Bbp = B + (size_t)bz * strideB; }
    } else {
        Bbp = B + (size_t)bz * strideB;
    }

    int bx = blockIdx.x, by = blockIdx.y;
    if constexpr (SWZ == 1) {
        int nwg = gridDim.x * gridDim.y;
        int bid = blockIdx.x + gridDim.x * blockIdx.y;
        int cpx = nwg >> 3;
        int swz = (bid & 7) * cpx + (bid >> 3);
        bx = swz % gridDim.x;
        by = swz / gridDim.x;
    } else if constexpr (SWZ == 2) {
        int bid = blockIdx.x + gridDim.x * blockIdx.y;
        int xcd = bid & 7;
        int idx = bid >> 3;
        int rpr = gridDim.y >> 2;
        int cpr = gridDim.x >> 1;
        int row0 = (xcd >> 1) * rpr;
        int col0 = (xcd & 1) * cpr;
        by = row0 + idx / cpr;
        bx = col0 + idx % cpr;
    }
    int m0 = by * BM, n0 = bx * BN;
    int tid = threadIdx.x, wave = tid >> 6, lane = tid & 63;
    int wr = wave >> 1, wc = wave & 1;
    int lr = lane & 15, lg = lane >> 4;

    auto stage = [&](int buf, int k0) {
        us* Asb = smem + buf * BUFSZ;
        us* Bsb = Asb + AE;
#pragma unroll
        for (int ch = wave; ch < ACH; ch += 4) {
            int e0 = ch * 512 + lane * 8;
            int kb = e0 / (BM * 32);
            int rem = e0 - kb * (BM * 32);
            int rr = rem >> 5;
            int gslot = ((rem & 31) >> 3) ^ ((rr >> 1) & 3);
            gload_lds16(Ab + (size_t)(m0 + rr) * lda + k0 + kb * 32 + gslot * 8,
                        Asb + ch * 512);
        }
#pragma unroll
        for (int ch = wave; ch < BCH; ch += 4) {
            int e0 = ch * 512 + lane * 8;
            int kb = e0 / (BN * 32);
            int rem = e0 - kb * (BN * 32);
            int rr = rem >> 5;
            int gslot = ((rem & 31) >> 3) ^ ((rr >> 1) & 3);
            gload_lds16(Bbp + (size_t)(n0 + rr) * ldb + k0 + kb * 32 + gslot * 8,
                        Bsb + ch * 512);
        }
    };

    f32x4 acc[MI][NI];
#pragma unroll
    for (int i = 0; i < MI; ++i)
#pragma unroll
        for (int j = 0; j < NI; ++j) acc[i][j] = (f32x4){0.f, 0.f, 0.f, 0.f};

    stage(0, 0);
    asm volatile("s_waitcnt vmcnt(0)" ::: "memory");
    __syncthreads();

    int nsteps = K / BK;
    for (int t = 0; t < nsteps; ++t) {
        int cur = t & 1;
        if (t + 1 < nsteps) stage(cur ^ 1, (t + 1) * BK);
        const us* As = smem + cur * BUFSZ;
        const us* Bs = As + AE;
#pragma unroll
        for (int kb = 0; kb < BK / 32; ++kb) {
            const us* Abase = As + kb * BM * 32;
            const us* Bbase = Bs + kb * BN * 32;
            f16x8 a[MI], b[NI];
#pragma unroll
            for (int x = 0; x < MI; ++x) {
                int row = wr * WM + x * 16 + lr;
                a[x] = *reinterpret_cast<const f16x8*>(
                    &Abase[row * 32 + ((lg ^ ((row >> 1) & 3)) << 3)]);
            }
#pragma unroll
            for (int x = 0; x < NI; ++x) {
                int row = wc * WN + x * 16 + lr;
                b[x] = *reinterpret_cast<const f16x8*>(
                    &Bbase[row * 32 + ((lg ^ ((row >> 1) & 3)) << 3)]);
            }
#pragma unroll
            for (int mi = 0; mi < MI; ++mi)
#pragma unroll
                for (int ni = 0; ni < NI; ++ni)
                    acc[mi][ni] = __builtin_amdgcn_mfma_f32_16x16x32_f16(a[mi], b[ni], acc[mi][ni], 0, 0, 0);
        }
        asm volatile("s_waitcnt vmcnt(0)" ::: "memory");
        __syncthreads();
    }

    constexpr int SP = BN + 4;
    float* sst = reinterpret_cast<float*>(smem);
    constexpr int CSEG = BN / 8;
    int rl = tid >> 3;
    int cb = (tid & 7) * CSEG;
#pragma unroll
    for (int mi = 0; mi < MI; ++mi) {
        __syncthreads();
#pragma unroll
        for (int ni = 0; ni < NI; ++ni) {
#pragma unroll
            for (int r = 0; r < 4; ++r)
                sst[(wr * 16 + lg * 4 + r) * SP + wc * WN + ni * 16 + lr] = acc[mi][ni][r];
        }
        __syncthreads();
        int grow = m0 + (rl >> 4) * WM + mi * 16 + (rl & 15);
        float bs = 0.f;
        if constexpr (BIAS == 1) bs = biasp[grow];
#pragma unroll
        for (int j = 0; j < CSEG / 4; ++j) {
            int col = n0 + cb + j * 4;
            float4 v = *reinterpret_cast<const float4*>(&sst[rl * SP + cb + j * 4]);
            if constexpr (BIAS == 1) { v.x += bs; v.y += bs; v.z += bs; v.w += bs; }
            if constexpr (BIAS == 2) {
                const float4 bv = *reinterpret_cast<const float4*>(&biasp[col]);
                v.x += bv.x; v.y += bv.y; v.z += bv.z; v.w += bv.w;
            }
            size_t off = (size_t)bz * strideC + (size_t)grow * ldc + col;
            if constexpr (RESID) {
                const float4 rr4 = *reinterpret_cast<const float4*>(
                    &resid[(size_t)bz * strideR + (size_t)grow * ldc + col]);
                v.x += rr4.x; v.y += rr4.y; v.z += rr4.z; v.w += rr4.w;
            }
            if constexpr (EPI == 0) {
                *reinterpret_cast<float4*>(&((float*)out0)[off]) = v;
            } else {
                ull pk = (ull)f2h(v.x) | ((ull)f2h(v.y) << 16)
                       | ((ull)f2h(v.z) << 32) | ((ull)f2h(v.w) << 48);
                *reinterpret_cast<ull*>(&((us*)out0)[off]) = pk;
            }
        }
    }
}

// ------- fp16 MFMA GEMM (8-wave, 256x256, wave tile 128x64), dbuf, BK param ----
// BK=64: 8 barrier-pairs over K=512 (vs 16 at BK=32); LDS 2x64KB=128KB,
// 1 block/CU (occupancy proven non-limiting in r15/r16). kb-subtile loop
// preserves exact K-summation order (bit-identical to BK=32).
template <int SWZ, int BK>
__global__ __launch_bounds__(512) void mfma_gemm8w(
    const us* __restrict__ A, int lda, long long strideA,
    const us* __restrict__ B, int ldb, long long strideB,
    us* __restrict__ out0, int ldc, long long strideC,
    int K) {
    constexpr int BM = 256, BN = 256;
    constexpr int WM = 128, WN = 64;
    constexpr int MI = WM / 16, NI = WN / 16;  // 8, 4
    constexpr int AE = BM * BK, BE = BN * BK;
    constexpr int BUFSZ = AE + BE;
    constexpr int ACH = AE / 512, BCH = BE / 512;
    __shared__ __attribute__((aligned(16))) us smem[2 * BUFSZ];

    int bz = blockIdx.z;
    const us* Ab = A + (size_t)bz * strideA;
    const us* Bbp = B + (size_t)bz * strideB;

    int bx = blockIdx.x, by = blockIdx.y;
    if constexpr (SWZ == 2) {
        int bid = blockIdx.x + gridDim.x * blockIdx.y;
        int xcd = bid & 7;
        int idx = bid >> 3;
        int rpr = gridDim.y >> 2;
        int cpr = gridDim.x >> 1;
        int row0 = (xcd >> 1) * rpr;
        int col0 = (xcd & 1) * cpr;
        by = row0 + idx / cpr;
        bx = col0 + idx % cpr;
    }
    int m0 = by * BM, n0 = bx * BN;
    int tid = threadIdx.x, wave = tid >> 6, lane = tid & 63;
    int wr = wave >> 2, wc = wave & 3;
    int lr = lane & 15, lg = lane >> 4;

    auto stage = [&](int buf, int k0) {
        us* Asb = smem + buf * BUFSZ;
        us* Bsb = Asb + AE;
#pragma unroll
        for (int ch = wave; ch < ACH; ch += 8) {
            int e0 = ch * 512 + lane * 8;
            int kb = e0 / (BM * 32);
            int rem = e0 - kb * (BM * 32);
            int rr = rem >> 5;
            int gslot = ((rem & 31) >> 3) ^ ((rr >> 1) & 3);
            gload_lds16(Ab + (size_t)(m0 + rr) * lda + k0 + kb * 32 + gslot * 8,
                        Asb + ch * 512);
        }
#pragma unroll
        for (int ch = wave; ch < BCH; ch += 8) {
            int e0 = ch * 512 + lane * 8;
            int kb = e0 / (BN * 32);
            int rem = e0 - kb * (BN * 32);
            int rr = rem >> 5;
            int gslot = ((rem & 31) >> 3) ^ ((rr >> 1) & 3);
            gload_lds16(Bbp + (size_t)(n0 + rr) * ldb + k0 + kb * 32 + gslot * 8,
                        Bsb + ch * 512);
        }
    };

    f32x4 acc[MI][NI];
#pragma unroll
    for (int i = 0; i < MI; ++i)
#pragma unroll
        for (int j = 0; j < NI; ++j) acc[i][j] = (f32x4){0.f, 0.f, 0.f, 0.f};

    stage(0, 0);
    asm volatile("s_waitcnt vmcnt(0)" ::: "memory");
    __syncthreads();

    int nsteps = K / BK;
    for (int t = 0; t < nsteps; ++t) {
        int cur = t & 1;
        if (t + 1 < nsteps) stage(cur ^ 1, (t + 1) * BK);
        const us* As = smem + cur * BUFSZ;
        const us* Bs = As + AE;
#pragma unroll
        for (int kb = 0; kb < BK / 32; ++kb) {
            const us* Abase = As + kb * BM * 32;
            const us* Bbase = Bs + kb * BN * 32;
            f16x8 a[MI], b[NI];
#pragma unroll
            for (int x = 0; x < MI; ++x) {
                int row = wr * WM + x * 16 + lr;
                a[x] = *reinterpret_cast<const f16x8*>(
                    &Abase[row * 32 + ((lg ^ ((row >> 1) & 3)) << 3)]);
            }
#pragma unroll
            for (int x = 0; x < NI; ++x) {
                int row = wc * WN + x * 16 + lr;
                b[x] = *reinterpret_cast<const f16x8*>(
                    &Bbase[row * 32 + ((lg ^ ((row >> 1) & 3)) << 3)]);
            }
#pragma unroll
            for (int mi = 0; mi < MI; ++mi)
#pragma unroll
                for (int ni = 0; ni < NI; ++ni)
                    acc[mi][ni] = __builtin_amdgcn_mfma_f32_16x16x32_f16(a[mi], b[ni], acc[mi][ni], 0, 0, 0);
        }
        asm volatile("s_waitcnt vmcnt(0)" ::: "memory");
        __syncthreads();
    }

#pragma unroll
    for (int mi = 0; mi < MI; ++mi) {
        int row = m0 + wr * WM + mi * 16 + lg * 4;
#pragma unroll
        for (int ni = 0; ni < NI; ++ni) {
            int col = n0 + wc * WN + ni * 16 + lr;
#pragma unroll
            for (int r = 0; r < 4; ++r) {
                size_t off = (size_t)bz * strideC + (size_t)(row + r) * ldc + col;
                out0[off] = f2h(acc[mi][ni][r]);
            }
        }
    }
}

// ------- row softmax fp16 IN-PLACE (S row -> normalized P row) -------
__global__ __launch_bounds__(256) void softmax_kernel(us* __restrict__ S) {
    us* rowp = S + (size_t)blockIdx.y * ((size_t)Nn * Nn) + (size_t)blockIdx.x * Nn;
    f16x8* r8 = reinterpret_cast<f16x8*>(rowp);
    int t = threadIdx.x;
    float f[16];
    float mx = -1e30f;
#pragma unroll
    for (int j = 0; j < 2; ++j) {
        f16x8 v = r8[t + 256 * j];
#pragma unroll
        for (int e = 0; e < 8; ++e) {
            f[j * 8 + e] = (float)v[e];
            mx = fmaxf(mx, f[j * 8 + e]);
        }
    }
    for (int off = 32; off; off >>= 1) mx = fmaxf(mx, __shfl_down(mx, off));
    __shared__ float redm[4], reds[4];
    int wid = t >> 6;
    if ((t & 63) == 0) redm[wid] = mx;
    __syncthreads();
    mx = fmaxf(fmaxf(redm[0], redm[1]), fmaxf(redm[2], redm[3]));
    float s = 0.f;
#pragma unroll
    for (int j = 0; j < 16; ++j) {
        f[j] = __expf(f[j] - mx);
        s += f[j];
    }
    for (int off = 32; off; off >>= 1) s += __shfl_down(s, off);
    if ((t & 63) == 0) reds[wid] = s;
    __syncthreads();
    s = reds[0] + reds[1] + reds[2] + reds[3];
    float inv = 1.f / s;
#pragma unroll
    for (int j = 0; j < 2; ++j) {
        f16x8 o;
#pragma unroll
        for (int e = 0; e < 8; ++e) o[e] = (_Float16)(f[j * 8 + e] * inv);
        r8[t + 256 * j] = o;
    }
}

extern "C" void kernel_launch(void* const* d_in, const int* in_sizes, int n_in,
                              void* d_out, int out_size, void* d_ws, size_t ws_size,
                              hipStream_t stream) {
    const float* content = (const float*)d_in[0];
    const float* style   = (const float*)d_in[1];
    const float* f_w = (const float*)d_in[2];
    const float* f_b = (const float*)d_in[3];
    const float* g_w = (const float*)d_in[4];
    const float* g_b = (const float*)d_in[5];
    const float* h_w = (const float*)d_in[6];
    const float* h_b = (const float*)d_in[7];
    const float* o_w = (const float*)d_in[8];
    const float* o_b = (const float*)d_in[9];
    float* out = (float*)d_out;
    char* ws = (char*)d_ws;

    const size_t PB   = (size_t)Cc * Nn;
    const size_t TEN  = PB * Bb;
    const size_t SMAT = (size_t)Nn * Nn;

    us* FT  = (us*)ws;
    us* GT  = FT + TEN;                        // contiguous after FT (fused F/G out)
    us* Hbf = GT + TEN;
    us* OT  = Hbf + TEN;
    us* fwh = OT + TEN;
    us* gwh = fwh + Cc * Cc;
    us* hwb = gwh + Cc * Cc;
    us* owb = hwb + Cc * Cc;
    float* meanC = (float*)(owb + Cc * Cc);
    float* rstdC = meanC + Bb * Cc;
    float* meanS = rstdC + Bb * Cc;
    float* rstdS = meanS + Bb * Cc;
    us* CN = (us*)(rstdS + Bb * Cc);
    us* SN = CN + TEN;                         // contiguous after CN (fused F/G in)
    us* SR = SN + TEN;
    us* S4 = CN;   // overlays dead CN/SN/SR after convs

    stats2_kernel<<<2 * Bb * Cc, 256, 0, stream>>>(content, style,
                                                   meanC, rstdC, meanS, rstdS);

    pack_all<<<dim3(Nn / 64, Cc / 64, 2 * Bb), 256, 0, stream>>>(
        content, style, meanC, rstdC, meanS, rstdS, CN, SN, SR);
    pack_w<<<(Cc * Cc + 255) / 256, 256, 0, stream>>>(f_w, g_w, h_w, o_w,
                                                      fwh, gwh, hwb, owb);

    // FUSED F+G convs: z<4 -> F^T = CN.f_w + f_b; z>=4 -> G^T = SN.g_w + g_b
    mfma_gemm<1, 2, false, 64, 64, 64, 1><<<dim3(Cc / 64, Nn / 64, 2 * Bb), 256, 0, stream>>>(
        CN, Cc, (long long)PB, fwh, gwh, Cc, 0,
        FT, Cc, (long long)PB, f_b, g_b, nullptr, 0, Cc);
    // H[c'][s] = sum_c h_w[c'][c] SR[s][c] + h_b[c']
    mfma_gemm<1, 1, false, 64, 64, 64, 1><<<dim3(Nn / 64, Cc / 64, Bb), 256, 0, stream>>>(
        hwb, Cc, 0, SR, nullptr, Cc, (long long)PB,
        Hbf, Nn, (long long)PB, h_b, nullptr, nullptr, 0, Cc);

    // S[q][s] = F^T . G^T  (M=N=4096,K=512): 8-wave 256x256, BK=64 (8 barrier-pairs)
    mfma_gemm8w<2, 64><<<dim3(Nn / 256, Nn / 256, Bb), 512, 0, stream>>>(
        FT, Cc, (long long)PB, GT, Cc, (long long)PB,
        S4, Nn, (long long)SMAT, Cc);
    softmax_kernel<<<dim3(Nn, Bb), 256, 0, stream>>>(S4);
    // O^T[q][c'] = P . H  (M=4096,N=512,K=4096)
    mfma_gemm<1, 0, false, 128, 128, 64, 2><<<dim3(Cc / 128, Nn / 128, Bb), 256, 0, stream>>>(
        S4, Nn, (long long)SMAT, Hbf, nullptr, Nn, (long long)PB,
        OT, Cc, (long long)PB, nullptr, nullptr, nullptr, 0, Nn);

    // out = o_w . O^T + o_b + content
    mfma_gemm<0, 1, true, 64, 64, 64, 1><<<dim3(Nn / 64, Cc / 64, Bb), 256, 0, stream>>>(
        owb, Cc, 0, OT, nullptr, Cc, (long long)PB,
        out, Nn, (long long)PB, o_b, nullptr, content, (long long)PB, Cc);
}